// Round 5
// baseline (6396.985 us; speedup 1.0000x reference)
//
#include <hip/hip_runtime.h>
#include <math.h>

#define N_NODES 50000
#define N_EDGES 400000

// ---------------- degree / dinv ----------------
__global__ void k_deg_init(float* __restrict__ deg, int n) {
    int i = blockIdx.x * blockDim.x + threadIdx.x;
    if (i < n) deg[i] = 1.0f;  // self-loop
}

__global__ void k_deg_count(const int* __restrict__ dst, float* __restrict__ deg, int e) {
    int i = blockIdx.x * blockDim.x + threadIdx.x;
    if (i < e) atomicAdd(&deg[dst[i]], 1.0f);
}

__global__ void k_dinv(float* __restrict__ deg, int n) {
    int i = blockIdx.x * blockDim.x + threadIdx.x;
    if (i < n) deg[i] = rsqrtf(deg[i]);  // deg >= 1 always
}

// ---- GEMM: G[r, j] = dinv[r] * sum_k A[r,k] * W[k, wc0 + j],  j in [0, Ncols)
// G compact with row stride Ncols. W row stride wld. BM=64,BN=64,BK=16,
// 256 threads, 4x4 micro-tile.
__global__ __launch_bounds__(256) void k_gemm_scaled(
    const float* __restrict__ A, const float* __restrict__ W,
    const float* __restrict__ dinv, float* __restrict__ G,
    int M, int K, int Ncols, int wld, int wc0)
{
    __shared__ float As[16][64];   // [k][m]
    __shared__ float Bs[16][64];   // [k][n]
    const int tid = threadIdx.x;
    const int m0 = blockIdx.x * 64;
    const int n0 = blockIdx.y * 64;
    const int tx = tid & 15, ty = tid >> 4;
    const int a_r = tid >> 2, a_k4 = (tid & 3) << 2;
    const int b_k = tid >> 4, b_n = (tid & 15) << 2;
    const int arow = m0 + a_r;
    const bool rowok = arow < M;

    float acc[4][4] = {{0.f, 0.f, 0.f, 0.f}};

    for (int k0 = 0; k0 < K; k0 += 16) {
        float4 av = make_float4(0.f, 0.f, 0.f, 0.f);
        if (rowok) av = *(const float4*)&A[(size_t)arow * K + k0 + a_k4];
        float4 bv = *(const float4*)&W[(size_t)(k0 + b_k) * wld + wc0 + n0 + b_n];
        __syncthreads();
        As[a_k4 + 0][a_r] = av.x;
        As[a_k4 + 1][a_r] = av.y;
        As[a_k4 + 2][a_r] = av.z;
        As[a_k4 + 3][a_r] = av.w;
        *(float4*)&Bs[b_k][b_n] = bv;
        __syncthreads();
#pragma unroll
        for (int k = 0; k < 16; ++k) {
            float4 a = *(const float4*)&As[k][ty << 2];
            float4 b = *(const float4*)&Bs[k][tx << 2];
            float aa[4] = {a.x, a.y, a.z, a.w};
            float bb[4] = {b.x, b.y, b.z, b.w};
#pragma unroll
            for (int i = 0; i < 4; ++i)
#pragma unroll
                for (int j = 0; j < 4; ++j)
                    acc[i][j] = fmaf(aa[i], bb[j], acc[i][j]);
        }
    }

#pragma unroll
    for (int i = 0; i < 4; ++i) {
        int r = m0 + (ty << 2) + i;
        if (r < M) {
            float s = dinv[r];
            float4 v = make_float4(acc[i][0] * s, acc[i][1] * s, acc[i][2] * s, acc[i][3] * s);
            *(float4*)&G[(size_t)r * Ncols + n0 + (tx << 2)] = v;
        }
    }
}

// ---------------- last-layer GEMM: K=64, N=2 ----------------
__global__ void k_gemm2(const float* __restrict__ A, const float* __restrict__ W,
                        const float* __restrict__ dinv, float* __restrict__ G, int M, int K)
{
    int i = blockIdx.x * blockDim.x + threadIdx.x;
    if (i >= M) return;
    float a0 = 0.f, a1 = 0.f;
    for (int k = 0; k < K; k += 4) {
        float4 a = *(const float4*)&A[(size_t)i * K + k];
        a0 += a.x * W[(k + 0) * 2 + 0] + a.y * W[(k + 1) * 2 + 0]
            + a.z * W[(k + 2) * 2 + 0] + a.w * W[(k + 3) * 2 + 0];
        a1 += a.x * W[(k + 0) * 2 + 1] + a.y * W[(k + 1) * 2 + 1]
            + a.z * W[(k + 2) * 2 + 1] + a.w * W[(k + 3) * 2 + 1];
    }
    float s = dinv[i];
    G[2 * (size_t)i + 0] = s * a0;
    G[2 * (size_t)i + 1] = s * a1;
}

// ---- self-loop init: agg[i, c0+j] = g[i, j]  (g compact CH*4 cols) ----
template <int CH>
__global__ void k_selfcopy(const float* __restrict__ g, float* __restrict__ agg,
                           int ldAgg, int c0)
{
    int idx = blockIdx.x * blockDim.x + threadIdx.x;
    if (idx >= N_NODES * CH) return;
    int i = idx / CH, c = idx % CH;
    float4 v = *(const float4*)&g[(size_t)i * (CH * 4) + c * 4];
    *(float4*)&agg[(size_t)i * ldAgg + c0 + c * 4] = v;
}

// ---- flat float4 copy (for identical-layout buffers) ----
__global__ void k_copy4(const float4* __restrict__ s, float4* __restrict__ d, int n4) {
    int i = blockIdx.x * blockDim.x + threadIdx.x;
    if (i < n4) d[i] = s[i];
}

// ---- edge scatter: agg[dst, c0+j] += g[src, j] ----
template <int CH>
__global__ __launch_bounds__(256) void k_scatter(
    const int* __restrict__ src, const int* __restrict__ dst,
    const float* __restrict__ g, float* __restrict__ agg, int ldAgg, int c0)
{
    long long tid = (long long)blockIdx.x * 256 + threadIdx.x;
    int e = (int)(tid / CH);
    int c = (int)(tid % CH);
    if (e >= N_EDGES) return;
    int s = src[e], d = dst[e];
    float4 v = *(const float4*)&g[(size_t)s * (CH * 4) + c * 4];
    float* o = &agg[(size_t)d * ldAgg + c0 + c * 4];
    atomicAdd(o + 0, v.x);
    atomicAdd(o + 1, v.y);
    atomicAdd(o + 2, v.z);
    atomicAdd(o + 3, v.w);
}

__global__ void k_scatter2(const int* __restrict__ src, const int* __restrict__ dst,
                           const float* __restrict__ g, float* __restrict__ agg)
{
    int e = blockIdx.x * blockDim.x + threadIdx.x;
    if (e >= N_EDGES) return;
    int s = src[e], d = dst[e];
    float2 v = *(const float2*)&g[2 * (size_t)s];
    atomicAdd(&agg[2 * (size_t)d + 0], v.x);
    atomicAdd(&agg[2 * (size_t)d + 1], v.y);
}

// ---------------- epilogue: h = [relu](dinv*agg + b), in place ----------------
template <int OUT>
__global__ void k_epi(float* __restrict__ agg, const float* __restrict__ bias,
                      const float* __restrict__ dinv, int M, int relu)
{
    constexpr int CH = OUT / 4;
    int idx = blockIdx.x * blockDim.x + threadIdx.x;
    if (idx >= M * CH) return;
    int i = idx / CH;
    int c = idx % CH;
    float s = dinv[i];
    float4 v = *(const float4*)&agg[(size_t)idx * 4];
    float4 b = *(const float4*)&bias[c * 4];
    v.x = v.x * s + b.x;
    v.y = v.y * s + b.y;
    v.z = v.z * s + b.z;
    v.w = v.w * s + b.w;
    if (relu) {
        v.x = fmaxf(v.x, 0.f); v.y = fmaxf(v.y, 0.f);
        v.z = fmaxf(v.z, 0.f); v.w = fmaxf(v.w, 0.f);
    }
    *(float4*)&agg[(size_t)idx * 4] = v;
}

// ---------------- final: dinv*agg + b -> log_softmax -> out ----------------
__global__ void k_final(const float* __restrict__ agg, const float* __restrict__ bias,
                        const float* __restrict__ dinv, float* __restrict__ out, int M)
{
    int i = blockIdx.x * blockDim.x + threadIdx.x;
    if (i >= M) return;
    float s = dinv[i];
    float o0 = agg[2 * (size_t)i + 0] * s + bias[0];
    float o1 = agg[2 * (size_t)i + 1] * s + bias[1];
    float m = fmaxf(o0, o1);
    float lse = m + logf(expf(o0 - m) + expf(o1 - m));
    out[2 * (size_t)i + 0] = o0 - lse;
    out[2 * (size_t)i + 1] = o1 - lse;
}

extern "C" void kernel_launch(void* const* d_in, const int* in_sizes, int n_in,
                              void* d_out, int out_size, void* d_ws, size_t ws_size,
                              hipStream_t stream) {
    const float* x   = (const float*)d_in[0];
    const int*   ei  = (const int*)d_in[1];
    const int*   src = ei;
    const int*   dst = ei + N_EDGES;
    const float* W1 = (const float*)d_in[2];  const float* b1 = (const float*)d_in[3];
    const float* W2 = (const float*)d_in[4];  const float* b2 = (const float*)d_in[5];
    const float* W3 = (const float*)d_in[6];  const float* b3 = (const float*)d_in[7];
    const float* W4 = (const float*)d_in[8];  const float* b4 = (const float*)d_in[9];
    const float* W5 = (const float*)d_in[10]; const float* b5 = (const float*)d_in[11];
    float* out = (float*)d_out;

    // Workspace layout (total ~219.4 MB):
    //   dinv  : 50000 f32                (1 MB reserved)
    //   P0    : [50000,512] f32  102.4 MB  (h2)
    //   P1    : [50000,256] f32   51.2 MB  (h1, then h3)
    //   PG    : [50000,256] f32   51.2 MB  (shared compact g)
    //   P2    : [50000, 64] f32   12.8 MB  (h4)
    //   P3/P4 : [50000,  2] f32    0.4 MB each (logits / agg)
    char* ws = (char*)d_ws;
    float* dinv = (float*)ws;
    float* P0 = (float*)(ws + (1 << 20));
    float* P1 = P0 + (size_t)N_NODES * 512;
    float* PG = P1 + (size_t)N_NODES * 256;
    float* P2 = PG + (size_t)N_NODES * 256;
    float* P3 = P2 + (size_t)N_NODES * 64;
    float* P4 = P3 + (size_t)N_NODES * 2;

    const int T = 256;
    k_deg_init<<<(N_NODES + T - 1) / T, T, 0, stream>>>(dinv, N_NODES);
    k_deg_count<<<(N_EDGES + T - 1) / T, T, 0, stream>>>(dst, dinv, N_EDGES);
    k_dinv<<<(N_NODES + T - 1) / T, T, 0, stream>>>(dinv, N_NODES);

    dim3 g256((N_NODES + 63) / 64, 4);   // 256 output cols
    dim3 g64((N_NODES + 63) / 64, 1);    // 64 output cols
    const int selfB64 = (N_NODES * 64 + T - 1) / T;
    const int selfB16 = (N_NODES * 16 + T - 1) / T;
    const int scatB64 = (int)(((long long)N_EDGES * 64 + 255) / 256);
    const int scatB16 = (int)(((long long)N_EDGES * 16 + 255) / 256);

    // L1: x[,128] @ W1[128,256] -> h1 in P1
    k_gemm_scaled<<<g256, T, 0, stream>>>(x, W1, dinv, PG, N_NODES, 128, 256, 256, 0);
    k_selfcopy<64><<<selfB64, T, 0, stream>>>(PG, P1, 256, 0);
    k_scatter<64><<<scatB64, T, 0, stream>>>(src, dst, PG, P1, 256, 0);
    k_epi<256><<<selfB64, T, 0, stream>>>(P1, b1, dinv, N_NODES, 1);

    // L2: h1[,256] @ W2[256,512] -> h2 in P0, two 256-col halves
    for (int hh = 0; hh < 2; ++hh) {
        k_gemm_scaled<<<g256, T, 0, stream>>>(P1, W2, dinv, PG, N_NODES, 256, 256, 512, 256 * hh);
        k_selfcopy<64><<<selfB64, T, 0, stream>>>(PG, P0, 512, 256 * hh);
        k_scatter<64><<<scatB64, T, 0, stream>>>(src, dst, PG, P0, 512, 256 * hh);
    }
    k_epi<512><<<(N_NODES * 128 + T - 1) / T, T, 0, stream>>>(P0, b2, dinv, N_NODES, 1);

    // L3: h2[,512] @ W3[512,256] -> h3 in P1
    k_gemm_scaled<<<g256, T, 0, stream>>>(P0, W3, dinv, PG, N_NODES, 512, 256, 256, 0);
    k_selfcopy<64><<<selfB64, T, 0, stream>>>(PG, P1, 256, 0);
    k_scatter<64><<<scatB64, T, 0, stream>>>(src, dst, PG, P1, 256, 0);
    k_epi<256><<<selfB64, T, 0, stream>>>(P1, b3, dinv, N_NODES, 1);

    // L4: h3[,256] @ W4[256,64] -> h4 in P2
    k_gemm_scaled<<<g64, T, 0, stream>>>(P1, W4, dinv, PG, N_NODES, 256, 64, 64, 0);
    k_selfcopy<16><<<selfB16, T, 0, stream>>>(PG, P2, 64, 0);
    k_scatter<16><<<scatB16, T, 0, stream>>>(src, dst, PG, P2, 64, 0);
    k_epi<64><<<selfB16, T, 0, stream>>>(P2, b4, dinv, N_NODES, 1);

    // L5: h4[,64] @ W5[64,2] -> logits -> log_softmax
    k_gemm2<<<(N_NODES + T - 1) / T, T, 0, stream>>>(P2, W5, dinv, P3, N_NODES, 64);
    // self-loop init: P3 and P4 are identical compact [50000,2] layouts -> flat copy
    k_copy4<<<(N_NODES * 2 / 4 + T - 1) / T, T, 0, stream>>>((const float4*)P3, (float4*)P4, N_NODES * 2 / 4);
    k_scatter2<<<(N_EDGES + T - 1) / T, T, 0, stream>>>(src, dst, P3, P4);
    k_final<<<(N_NODES + T - 1) / T, T, 0, stream>>>(P4, b5, dinv, out, N_NODES);
}

// Round 6
// 917.751 us; speedup vs baseline: 6.9703x; 6.9703x over previous
//
#include <hip/hip_runtime.h>
#include <math.h>

#define N_NODES 50000
#define N_EDGES 400000

// ================= CSR build =================
__global__ void k_zero_i(int* __restrict__ p, int n) {
    int i = blockIdx.x * blockDim.x + threadIdx.x;
    if (i < n) p[i] = 0;
}

__global__ void k_count(const int* __restrict__ dst, int* __restrict__ cnt) {
    int e = blockIdx.x * blockDim.x + threadIdx.x;
    if (e < N_EDGES) atomicAdd(&cnt[dst[e]], 1);
}

// single-block scan: rowptr = exclusive prefix of cnt; dinv = rsqrt(cnt+1)
__global__ __launch_bounds__(1024) void k_scan(const int* __restrict__ cnt,
                                               int* __restrict__ rowptr,
                                               float* __restrict__ dinv, int n) {
    __shared__ int sm[1024];
    __shared__ int carry;
    if (threadIdx.x == 0) carry = 0;
    __syncthreads();
    for (int base = 0; base < n; base += 1024) {
        int i = base + threadIdx.x;
        int v = (i < n) ? cnt[i] : 0;
        sm[threadIdx.x] = v;
        __syncthreads();
        for (int off = 1; off < 1024; off <<= 1) {
            int t = (threadIdx.x >= (unsigned)off) ? sm[threadIdx.x - off] : 0;
            __syncthreads();
            sm[threadIdx.x] += t;
            __syncthreads();
        }
        if (i < n) {
            rowptr[i] = carry + sm[threadIdx.x] - v;   // exclusive
            dinv[i] = rsqrtf((float)(v + 1));          // + self-loop
        }
        __syncthreads();
        if (threadIdx.x == 0) carry += sm[1023];
        __syncthreads();
    }
    if (threadIdx.x == 0) rowptr[n] = carry;
}

__global__ void k_copy_i(const int* __restrict__ s, int* __restrict__ d, int n) {
    int i = blockIdx.x * blockDim.x + threadIdx.x;
    if (i < n) d[i] = s[i];
}

__global__ void k_fill(const int* __restrict__ src, const int* __restrict__ dst,
                       int* __restrict__ cursor, int* __restrict__ csr) {
    int e = blockIdx.x * blockDim.x + threadIdx.x;
    if (e >= N_EDGES) return;
    int d = dst[e];
    int pos = atomicAdd(&cursor[d], 1);
    csr[pos] = src[e];
}

// ================= row pre-scale: xs = dinv[i] * x =================
__global__ void k_rowscale(const float* __restrict__ x, const float* __restrict__ dinv,
                           float* __restrict__ xs) {
    int idx = blockIdx.x * blockDim.x + threadIdx.x;   // over N_NODES*32 float4s
    if (idx >= N_NODES * 32) return;
    int i = idx >> 5;
    float4 v = ((const float4*)x)[idx];
    float s = dinv[i];
    v.x *= s; v.y *= s; v.z *= s; v.w *= s;
    ((float4*)xs)[idx] = v;
}

// ================= CSR aggregation: o[i] = epi( dinv[i]*( g[i] + sum_{src->i} g[src] ) )
// one wave per node; lane owns VEC consecutive cols; W = 64*VEC.
// MODE 0: scale only.  MODE 1: relu(scale + bias).
template <int VEC, int MODE>
__global__ __launch_bounds__(256) void k_agg(
    const float* __restrict__ g, const int* __restrict__ rowptr,
    const int* __restrict__ csr, const float* __restrict__ dinv,
    const float* __restrict__ bias, float* __restrict__ o)
{
    constexpr int W = 64 * VEC;
    const int wave = threadIdx.x >> 6, lane = threadIdx.x & 63;
    const int node = blockIdx.x * 4 + wave;
    if (node >= N_NODES) return;
    const int col = lane * VEC;

    float acc[VEC];
    {
        const float* p = g + (size_t)node * W + col;
        if constexpr (VEC == 4) { float4 t = *(const float4*)p; acc[0]=t.x; acc[1]=t.y; acc[2]=t.z; acc[3]=t.w; }
        else if constexpr (VEC == 2) { float2 t = *(const float2*)p; acc[0]=t.x; acc[1]=t.y; }
        else acc[0] = *p;
    }
    const int beg = rowptr[node], end = rowptr[node + 1];
    for (int j = beg; j < end; ++j) {
        int s = csr[j];
        const float* p = g + (size_t)s * W + col;
        if constexpr (VEC == 4) { float4 t = *(const float4*)p; acc[0]+=t.x; acc[1]+=t.y; acc[2]+=t.z; acc[3]+=t.w; }
        else if constexpr (VEC == 2) { float2 t = *(const float2*)p; acc[0]+=t.x; acc[1]+=t.y; }
        else acc[0] += *p;
    }
    const float sc = dinv[node];
    float* po = o + (size_t)node * W + col;
    float r[VEC];
#pragma unroll
    for (int v = 0; v < VEC; ++v) {
        float t = sc * acc[v];
        if (MODE == 1) t = fmaxf(t + bias[col + v], 0.f);
        r[v] = t;
    }
    if constexpr (VEC == 4) *(float4*)po = make_float4(r[0], r[1], r[2], r[3]);
    else if constexpr (VEC == 2) *(float2*)po = make_float2(r[0], r[1]);
    else *po = r[0];
}

// 2-col aggregation (last layer), thread per node, scale only
__global__ void k_agg2(const float* __restrict__ g, const int* __restrict__ rowptr,
                       const int* __restrict__ csr, const float* __restrict__ dinv,
                       float* __restrict__ o) {
    int i = blockIdx.x * blockDim.x + threadIdx.x;
    if (i >= N_NODES) return;
    float2 a = *(const float2*)&g[2 * (size_t)i];
    int beg = rowptr[i], end = rowptr[i + 1];
    for (int j = beg; j < end; ++j) {
        int s = csr[j];
        float2 t = *(const float2*)&g[2 * (size_t)s];
        a.x += t.x; a.y += t.y;
    }
    float sc = dinv[i];
    o[2 * (size_t)i + 0] = sc * a.x;
    o[2 * (size_t)i + 1] = sc * a.y;
}

// ================= GEMM: G = epi(A @ W), BM=64,BN=64,BK=16, 4x4 micro-tile
// mode 0: t = dinv[r]*acc
// mode 1: t = relu(acc + bias[c])
// mode 2: t = dinv[r]*relu(acc + bias[c])
__global__ __launch_bounds__(256) void k_gemm(
    const float* __restrict__ A, const float* __restrict__ W,
    const float* __restrict__ dinv, const float* __restrict__ bias,
    float* __restrict__ G, int M, int K, int N, int mode)
{
    __shared__ float As[16][64];   // [k][m]
    __shared__ float Bs[16][64];   // [k][n]
    const int tid = threadIdx.x;
    const int m0 = blockIdx.x * 64;
    const int n0 = blockIdx.y * 64;
    const int tx = tid & 15, ty = tid >> 4;
    const int a_r = tid >> 2, a_k4 = (tid & 3) << 2;
    const int b_k = tid >> 4, b_n = (tid & 15) << 2;
    const int arow = m0 + a_r;
    const bool rowok = arow < M;

    float acc[4][4] = {{0.f, 0.f, 0.f, 0.f}};

    for (int k0 = 0; k0 < K; k0 += 16) {
        float4 av = make_float4(0.f, 0.f, 0.f, 0.f);
        if (rowok) av = *(const float4*)&A[(size_t)arow * K + k0 + a_k4];
        float4 bv = *(const float4*)&W[(size_t)(k0 + b_k) * N + n0 + b_n];
        __syncthreads();
        As[a_k4 + 0][a_r] = av.x;
        As[a_k4 + 1][a_r] = av.y;
        As[a_k4 + 2][a_r] = av.z;
        As[a_k4 + 3][a_r] = av.w;
        *(float4*)&Bs[b_k][b_n] = bv;
        __syncthreads();
#pragma unroll
        for (int k = 0; k < 16; ++k) {
            float4 a = *(const float4*)&As[k][ty << 2];
            float4 b = *(const float4*)&Bs[k][tx << 2];
            float aa[4] = {a.x, a.y, a.z, a.w};
            float bb[4] = {b.x, b.y, b.z, b.w};
#pragma unroll
            for (int i = 0; i < 4; ++i)
#pragma unroll
                for (int j = 0; j < 4; ++j)
                    acc[i][j] = fmaf(aa[i], bb[j], acc[i][j]);
        }
    }

    float4 bb4 = make_float4(0.f, 0.f, 0.f, 0.f);
    if (mode >= 1) bb4 = *(const float4*)&bias[n0 + (tx << 2)];
    const float bcol[4] = {bb4.x, bb4.y, bb4.z, bb4.w};

#pragma unroll
    for (int i = 0; i < 4; ++i) {
        int r = m0 + (ty << 2) + i;
        if (r < M) {
            float s = dinv[r];
            float o[4];
#pragma unroll
            for (int j = 0; j < 4; ++j) {
                float t = acc[i][j];
                if (mode == 0)      t = s * t;
                else if (mode == 1) t = fmaxf(t + bcol[j], 0.f);
                else                t = s * fmaxf(t + bcol[j], 0.f);
                o[j] = t;
            }
            *(float4*)&G[(size_t)r * N + n0 + (tx << 2)] = make_float4(o[0], o[1], o[2], o[3]);
        }
    }
}

// ================= last-layer GEMM: K=64, N=2, out = dinv[i]*(A@W5) =================
__global__ void k_gemm2(const float* __restrict__ A, const float* __restrict__ W,
                        const float* __restrict__ dinv, float* __restrict__ G, int M, int K)
{
    int i = blockIdx.x * blockDim.x + threadIdx.x;
    if (i >= M) return;
    float a0 = 0.f, a1 = 0.f;
    for (int k = 0; k < K; k += 4) {
        float4 a = *(const float4*)&A[(size_t)i * K + k];
        a0 += a.x * W[(k + 0) * 2 + 0] + a.y * W[(k + 1) * 2 + 0]
            + a.z * W[(k + 2) * 2 + 0] + a.w * W[(k + 3) * 2 + 0];
        a1 += a.x * W[(k + 0) * 2 + 1] + a.y * W[(k + 1) * 2 + 1]
            + a.z * W[(k + 2) * 2 + 1] + a.w * W[(k + 3) * 2 + 1];
    }
    float s = dinv[i];
    G[2 * (size_t)i + 0] = s * a0;
    G[2 * (size_t)i + 1] = s * a1;
}

// ================= final: logits + b5 -> log_softmax =================
__global__ void k_final(const float* __restrict__ lg, const float* __restrict__ bias,
                        float* __restrict__ out, int M)
{
    int i = blockIdx.x * blockDim.x + threadIdx.x;
    if (i >= M) return;
    float o0 = lg[2 * (size_t)i + 0] + bias[0];
    float o1 = lg[2 * (size_t)i + 1] + bias[1];
    float m = fmaxf(o0, o1);
    float lse = m + logf(expf(o0 - m) + expf(o1 - m));
    out[2 * (size_t)i + 0] = o0 - lse;
    out[2 * (size_t)i + 1] = o1 - lse;
}

extern "C" void kernel_launch(void* const* d_in, const int* in_sizes, int n_in,
                              void* d_out, int out_size, void* d_ws, size_t ws_size,
                              hipStream_t stream) {
    const float* x   = (const float*)d_in[0];
    const int*   ei  = (const int*)d_in[1];
    const int*   src = ei;
    const int*   dst = ei + N_EDGES;
    const float* W1 = (const float*)d_in[2];  const float* b1 = (const float*)d_in[3];
    const float* W2 = (const float*)d_in[4];  const float* b2 = (const float*)d_in[5];
    const float* W3 = (const float*)d_in[6];  const float* b3 = (const float*)d_in[7];
    const float* W4 = (const float*)d_in[8];  const float* b4 = (const float*)d_in[9];
    const float* W5 = (const float*)d_in[10]; const float* b5 = (const float*)d_in[11];
    float* out = (float*)d_out;

    // ---- workspace layout (total ~208.8 MB) ----
    // [0,4MB): dinv@0, cnt@256K, rowptr@512K, cursor@768K, csr@1M
    // DATA = ws+4MB:
    //   R0 [50000*512 f32 = 102.4MB]: xs(0..6.4M floats), aggx(6.4M..12.8M); later h2;
    //                                 later g4s(0..3.2M), h4(3.2M..6.4M), g5s(6.4M..), logits(6.6M..)
    //   R1 [50000*256 f32 = 51.2MB]: h1s, later g3s
    //   R2 [50000*256 f32 = 51.2MB]: a2, later h3
    char* ws = (char*)d_ws;
    float* dinv   = (float*)(ws + 0);
    int*   cnt    = (int*)(ws + 256 * 1024);
    int*   rowptr = (int*)(ws + 512 * 1024);
    int*   cursor = (int*)(ws + 768 * 1024);
    int*   csr    = (int*)(ws + 1024 * 1024);
    float* R0 = (float*)(ws + 4 * 1024 * 1024);
    float* R1 = R0 + (size_t)N_NODES * 512;
    float* R2 = R1 + (size_t)N_NODES * 256;

    float* xs     = R0;
    float* aggx   = R0 + (size_t)N_NODES * 128;
    float* h1s    = R1;
    float* a2     = R2;
    float* h2     = R0;
    float* g3s    = R1;
    float* h3     = R2;
    float* g4s    = R0;
    float* h4     = R0 + (size_t)N_NODES * 64;
    float* g5s    = R0 + (size_t)N_NODES * 128;
    float* logits = R0 + (size_t)N_NODES * 132;

    const int T = 256;
    const int nodeB = (N_NODES + T - 1) / T;
    const int edgeB = (N_EDGES + T - 1) / T;
    const int aggB  = (N_NODES + 3) / 4;     // 4 waves/block, wave per node

    // ---- CSR build + dinv ----
    k_zero_i<<<nodeB, T, 0, stream>>>(cnt, N_NODES);
    k_count<<<edgeB, T, 0, stream>>>(dst, cnt);
    k_scan<<<1, 1024, 0, stream>>>(cnt, rowptr, dinv, N_NODES);
    k_copy_i<<<nodeB, T, 0, stream>>>(rowptr, cursor, N_NODES);
    k_fill<<<edgeB, T, 0, stream>>>(src, dst, cursor, csr);

    // ---- L1: aggregate first (128 cols), then GEMM ----
    k_rowscale<<<(N_NODES * 32 + T - 1) / T, T, 0, stream>>>(x, dinv, xs);
    k_agg<2, 0><<<aggB, T, 0, stream>>>(xs, rowptr, csr, dinv, nullptr, aggx);
    // h1s = dinv * relu(aggx@W1 + b1)
    k_gemm<<<dim3((N_NODES + 63) / 64, 4), T, 0, stream>>>(aggx, W1, dinv, b1, h1s, N_NODES, 128, 256, 2);

    // ---- L2: aggregate first (256 cols), then GEMM (512 out, no split) ----
    k_agg<4, 0><<<aggB, T, 0, stream>>>(h1s, rowptr, csr, dinv, nullptr, a2);
    // h2 = relu(a2@W2 + b2)
    k_gemm<<<dim3((N_NODES + 63) / 64, 8), T, 0, stream>>>(a2, W2, dinv, b2, h2, N_NODES, 256, 512, 1);

    // ---- L3: GEMM first (256 out < 512 in), then aggregate ----
    k_gemm<<<dim3((N_NODES + 63) / 64, 4), T, 0, stream>>>(h2, W3, dinv, nullptr, g3s, N_NODES, 512, 256, 0);
    // h3 = relu(dinv*agg(g3s) + b3)
    k_agg<4, 1><<<aggB, T, 0, stream>>>(g3s, rowptr, csr, dinv, b3, h3);

    // ---- L4: GEMM first (64 out), then aggregate ----
    k_gemm<<<dim3((N_NODES + 63) / 64, 1), T, 0, stream>>>(h3, W4, dinv, nullptr, g4s, N_NODES, 256, 64, 0);
    k_agg<1, 1><<<aggB, T, 0, stream>>>(g4s, rowptr, csr, dinv, b4, h4);

    // ---- L5: GEMM (2 out), aggregate, log_softmax ----
    k_gemm2<<<nodeB, T, 0, stream>>>(h4, W5, dinv, g5s, N_NODES, 64);
    k_agg2<<<nodeB, T, 0, stream>>>(g5s, rowptr, csr, dinv, logits);
    k_final<<<nodeB, T, 0, stream>>>(logits, b5, out, N_NODES);
}

// Round 7
// 747.259 us; speedup vs baseline: 8.5606x; 1.2282x over previous
//
#include <hip/hip_runtime.h>
#include <math.h>

#define N_NODES 50000
#define N_EDGES 400000

typedef __bf16 bf16x8 __attribute__((ext_vector_type(8)));
typedef float f32x4 __attribute__((ext_vector_type(4)));

// ---- split-precision helpers: f32 <-> (hi bf16 | lo bf16) packed in u32 ----
__device__ __forceinline__ unsigned bf16_rne(float v) {
    unsigned u = __float_as_uint(v);
    return (u + 0x7FFFu + ((u >> 16) & 1u)) >> 16;
}
__device__ __forceinline__ unsigned pack_split(float v) {
    unsigned hi = bf16_rne(v);
    float hif = __uint_as_float(hi << 16);
    unsigned lo = bf16_rne(v - hif);
    return (hi << 16) | lo;
}
__device__ __forceinline__ float unpack_ps(unsigned w) {
    return __uint_as_float(w & 0xFFFF0000u) + __uint_as_float(w << 16);
}

// ================= CSR build =================
__global__ void k_zero_i(int* __restrict__ p, int n) {
    int i = blockIdx.x * blockDim.x + threadIdx.x;
    if (i < n) p[i] = 0;
}

__global__ void k_count(const int* __restrict__ dst, int* __restrict__ cnt) {
    int e = blockIdx.x * blockDim.x + threadIdx.x;
    if (e < N_EDGES) atomicAdd(&cnt[dst[e]], 1);
}

__global__ __launch_bounds__(1024) void k_scan(const int* __restrict__ cnt,
                                               int* __restrict__ rowptr,
                                               float* __restrict__ dinv, int n) {
    __shared__ int sm[1024];
    __shared__ int carry;
    if (threadIdx.x == 0) carry = 0;
    __syncthreads();
    for (int base = 0; base < n; base += 1024) {
        int i = base + threadIdx.x;
        int v = (i < n) ? cnt[i] : 0;
        sm[threadIdx.x] = v;
        __syncthreads();
        for (int off = 1; off < 1024; off <<= 1) {
            int t = (threadIdx.x >= (unsigned)off) ? sm[threadIdx.x - off] : 0;
            __syncthreads();
            sm[threadIdx.x] += t;
            __syncthreads();
        }
        if (i < n) {
            rowptr[i] = carry + sm[threadIdx.x] - v;
            dinv[i] = rsqrtf((float)(v + 1));
        }
        __syncthreads();
        if (threadIdx.x == 0) carry += sm[1023];
        __syncthreads();
    }
    if (threadIdx.x == 0) rowptr[n] = carry;
}

__global__ void k_copy_i(const int* __restrict__ s, int* __restrict__ d, int n) {
    int i = blockIdx.x * blockDim.x + threadIdx.x;
    if (i < n) d[i] = s[i];
}

__global__ void k_fill(const int* __restrict__ src, const int* __restrict__ dst,
                       int* __restrict__ cursor, int* __restrict__ csr) {
    int e = blockIdx.x * blockDim.x + threadIdx.x;
    if (e >= N_EDGES) return;
    int d = dst[e];
    int pos = atomicAdd(&cursor[d], 1);
    csr[pos] = src[e];
}

// ================= weight prep: W[K][N] f32 -> Wt[N][K] packed =================
__global__ void k_wprep(const float* __restrict__ W, unsigned* __restrict__ Wtp, int K, int N) {
    int i = blockIdx.x * blockDim.x + threadIdx.x;
    if (i >= K * N) return;
    int k = i / N, n = i % N;
    Wtp[(size_t)n * K + k] = pack_split(W[i]);
}

// ================= xs = dinv[i] * x (f32) =================
__global__ void k_rowscale(const float* __restrict__ x, const float* __restrict__ dinv,
                           float* __restrict__ xs) {
    int idx = blockIdx.x * blockDim.x + threadIdx.x;
    if (idx >= N_NODES * 32) return;
    int i = idx >> 5;
    float4 v = ((const float4*)x)[idx];
    float s = dinv[i];
    v.x *= s; v.y *= s; v.z *= s; v.w *= s;
    ((float4*)xs)[idx] = v;
}

// ================= CSR aggregation =================
// o[i] = epi( dinv[i]*( g[i] + sum_{src->i} g[src] ) ); wave per node, VEC cols/lane.
// MODE 0: scale only. MODE 1: relu(scale + bias). INP/OUTP: packed-u32 vs f32.
template <int VEC, int MODE, int INP, int OUTP>
__global__ __launch_bounds__(256) void k_agg(
    const void* __restrict__ gv, const int* __restrict__ rowptr,
    const int* __restrict__ csr, const float* __restrict__ dinv,
    const float* __restrict__ bias, void* __restrict__ ov)
{
    constexpr int W = 64 * VEC;
    const int wave = threadIdx.x >> 6, lane = threadIdx.x & 63;
    const int node = blockIdx.x * 4 + wave;
    if (node >= N_NODES) return;
    const int col = lane * VEC;

    float acc[VEC];
#pragma unroll
    for (int v = 0; v < VEC; ++v) acc[v] = 0.f;

    auto fetch_add = [&](int r) {
        if constexpr (INP) {
            const unsigned* p = (const unsigned*)gv + (size_t)r * W + col;
            if constexpr (VEC == 4) {
                uint4 t = *(const uint4*)p;
                acc[0] += unpack_ps(t.x); acc[1] += unpack_ps(t.y);
                acc[2] += unpack_ps(t.z); acc[3] += unpack_ps(t.w);
            } else if constexpr (VEC == 2) {
                uint2 t = *(const uint2*)p;
                acc[0] += unpack_ps(t.x); acc[1] += unpack_ps(t.y);
            } else acc[0] += unpack_ps(*p);
        } else {
            const float* p = (const float*)gv + (size_t)r * W + col;
            if constexpr (VEC == 4) {
                float4 t = *(const float4*)p;
                acc[0] += t.x; acc[1] += t.y; acc[2] += t.z; acc[3] += t.w;
            } else if constexpr (VEC == 2) {
                float2 t = *(const float2*)p;
                acc[0] += t.x; acc[1] += t.y;
            } else acc[0] += *(const float*)p;
        }
    };

    fetch_add(node);                       // self-loop
    const int beg = rowptr[node], end = rowptr[node + 1];
    for (int j = beg; j < end; ++j) fetch_add(csr[j]);

    const float sc = dinv[node];
    float r[VEC];
#pragma unroll
    for (int v = 0; v < VEC; ++v) {
        float t = sc * acc[v];
        if (MODE == 1) t = fmaxf(t + bias[col + v], 0.f);
        r[v] = t;
    }
    if constexpr (OUTP) {
        unsigned* po = (unsigned*)ov + (size_t)node * W + col;
        if constexpr (VEC == 4)
            *(uint4*)po = make_uint4(pack_split(r[0]), pack_split(r[1]), pack_split(r[2]), pack_split(r[3]));
        else if constexpr (VEC == 2)
            *(uint2*)po = make_uint2(pack_split(r[0]), pack_split(r[1]));
        else *po = pack_split(r[0]);
    } else {
        float* po = (float*)ov + (size_t)node * W + col;
        if constexpr (VEC == 4) *(float4*)po = make_float4(r[0], r[1], r[2], r[3]);
        else if constexpr (VEC == 2) *(float2*)po = make_float2(r[0], r[1]);
        else *po = r[0];
    }
}

// 2-col aggregation (last layer), f32
__global__ void k_agg2(const float* __restrict__ g, const int* __restrict__ rowptr,
                       const int* __restrict__ csr, const float* __restrict__ dinv,
                       float* __restrict__ o) {
    int i = blockIdx.x * blockDim.x + threadIdx.x;
    if (i >= N_NODES) return;
    float2 a = *(const float2*)&g[2 * (size_t)i];
    int beg = rowptr[i], end = rowptr[i + 1];
    for (int j = beg; j < end; ++j) {
        int s = csr[j];
        float2 t = *(const float2*)&g[2 * (size_t)s];
        a.x += t.x; a.y += t.y;
    }
    float sc = dinv[i];
    o[2 * (size_t)i + 0] = sc * a.x;
    o[2 * (size_t)i + 1] = sc * a.y;
}

// ================= split-bf16 MFMA GEMM =================
// A (packed [M][K]) @ W (Wt packed [N][K]) -> Gp (packed [M][N]).
// BM=128, BN=64, BK=32; 256 threads = 4 waves; wave owns 32 rows x 64 cols.
// hi*hi + hi*lo + lo*hi via mfma_f32_16x16x32_bf16 (f32-level accuracy).
// mode 0: dinv[r]*acc; 1: relu(acc+bias); 2: dinv[r]*relu(acc+bias)
__global__ __launch_bounds__(256) void k_gemm_mfma(
    const unsigned* __restrict__ Ap, const unsigned* __restrict__ Wtp,
    const float* __restrict__ dinv, const float* __restrict__ bias,
    unsigned* __restrict__ Gp, int M, int K, int N, int mode)
{
    __shared__ char lds[24576];
    char* Ahi = lds;              // [128][32] bf16, swizzled
    char* Alo = lds + 8192;
    char* Bhi = lds + 16384;      // [64][32] bf16 (Bt: [n][k]), swizzled
    char* Blo = lds + 20480;

    const int tid = threadIdx.x;
    const int m0 = blockIdx.x * 128;
    const int n0 = blockIdx.y * 64;
    const int wv = tid >> 6, l = tid & 63;
    const int lr = l & 15, ls = l >> 4;

    // fragment read byte offsets (constant across K-steps)
    int aoff[2], boff[4];
#pragma unroll
    for (int h = 0; h < 2; ++h) {
        int row = wv * 32 + h * 16 + lr;
        aoff[h] = (row * 64 + ls * 16) ^ ((row & 7) << 4);
    }
#pragma unroll
    for (int j = 0; j < 4; ++j) {
        int row = j * 16 + lr;
        boff[j] = (row * 64 + ls * 16) ^ ((row & 7) << 4);
    }

    f32x4 acc[2][4] = {};

    for (int kt = 0; kt < K; kt += 32) {
        __syncthreads();
        // ---- stage A tile: 128x32 elems = 1024 chunks of 4 ----
#pragma unroll
        for (int p = 0; p < 4; ++p) {
            int c = p * 256 + tid;
            int row = c >> 3, c4 = (c & 7) * 4;
            int grow = m0 + row;
            uint4 w = make_uint4(0u, 0u, 0u, 0u);
            if (grow < M) w = *(const uint4*)&Ap[(size_t)grow * K + kt + c4];
            ushort4 hi, lo;
            hi.x = w.x >> 16; lo.x = w.x & 0xFFFFu;
            hi.y = w.y >> 16; lo.y = w.y & 0xFFFFu;
            hi.z = w.z >> 16; lo.z = w.z & 0xFFFFu;
            hi.w = w.w >> 16; lo.w = w.w & 0xFFFFu;
            int off = (row * 64 + c4 * 2) ^ ((row & 7) << 4);
            *(ushort4*)(Ahi + off) = hi;
            *(ushort4*)(Alo + off) = lo;
        }
        // ---- stage B tile: 64x32 = 512 chunks ----
#pragma unroll
        for (int p = 0; p < 2; ++p) {
            int c = p * 256 + tid;
            int row = c >> 3, c4 = (c & 7) * 4;
            uint4 w = *(const uint4*)&Wtp[(size_t)(n0 + row) * K + kt + c4];
            ushort4 hi, lo;
            hi.x = w.x >> 16; lo.x = w.x & 0xFFFFu;
            hi.y = w.y >> 16; lo.y = w.y & 0xFFFFu;
            hi.z = w.z >> 16; lo.z = w.z & 0xFFFFu;
            hi.w = w.w >> 16; lo.w = w.w & 0xFFFFu;
            int off = (row * 64 + c4 * 2) ^ ((row & 7) << 4);
            *(ushort4*)(Bhi + off) = hi;
            *(ushort4*)(Blo + off) = lo;
        }
        __syncthreads();

        bf16x8 ah[2], al[2], bh[4], bl[4];
#pragma unroll
        for (int h = 0; h < 2; ++h) {
            ah[h] = *(const bf16x8*)(Ahi + aoff[h]);
            al[h] = *(const bf16x8*)(Alo + aoff[h]);
        }
#pragma unroll
        for (int j = 0; j < 4; ++j) {
            bh[j] = *(const bf16x8*)(Bhi + boff[j]);
            bl[j] = *(const bf16x8*)(Blo + boff[j]);
        }
#pragma unroll
        for (int h = 0; h < 2; ++h)
#pragma unroll
            for (int j = 0; j < 4; ++j) {
                acc[h][j] = __builtin_amdgcn_mfma_f32_16x16x32_bf16(ah[h], bh[j], acc[h][j], 0, 0, 0);
                acc[h][j] = __builtin_amdgcn_mfma_f32_16x16x32_bf16(ah[h], bl[j], acc[h][j], 0, 0, 0);
                acc[h][j] = __builtin_amdgcn_mfma_f32_16x16x32_bf16(al[h], bh[j], acc[h][j], 0, 0, 0);
            }
    }

    // ---- epilogue: C frag (h,j): row = m0+wv*32+h*16+ls*4+reg, col = n0+j*16+lr ----
#pragma unroll
    for (int h = 0; h < 2; ++h)
#pragma unroll
        for (int j = 0; j < 4; ++j) {
            int col = n0 + j * 16 + lr;
            float bc = (mode >= 1) ? bias[col] : 0.f;
#pragma unroll
            for (int reg = 0; reg < 4; ++reg) {
                int r = m0 + wv * 32 + h * 16 + ls * 4 + reg;
                if (r < M) {
                    float t = acc[h][j][reg];
                    if (mode == 0)      t = dinv[r] * t;
                    else if (mode == 1) t = fmaxf(t + bc, 0.f);
                    else                t = dinv[r] * fmaxf(t + bc, 0.f);
                    Gp[(size_t)r * N + col] = pack_split(t);
                }
            }
        }
}

// ================= last-layer GEMM: K=64, N=2, f32 =================
__global__ void k_gemm2(const float* __restrict__ A, const float* __restrict__ W,
                        const float* __restrict__ dinv, float* __restrict__ G, int M, int K)
{
    int i = blockIdx.x * blockDim.x + threadIdx.x;
    if (i >= M) return;
    float a0 = 0.f, a1 = 0.f;
    for (int k = 0; k < K; k += 4) {
        float4 a = *(const float4*)&A[(size_t)i * K + k];
        a0 += a.x * W[(k + 0) * 2 + 0] + a.y * W[(k + 1) * 2 + 0]
            + a.z * W[(k + 2) * 2 + 0] + a.w * W[(k + 3) * 2 + 0];
        a1 += a.x * W[(k + 0) * 2 + 1] + a.y * W[(k + 1) * 2 + 1]
            + a.z * W[(k + 2) * 2 + 1] + a.w * W[(k + 3) * 2 + 1];
    }
    float s = dinv[i];
    G[2 * (size_t)i + 0] = s * a0;
    G[2 * (size_t)i + 1] = s * a1;
}

// ================= final: logits + b5 -> log_softmax =================
__global__ void k_final(const float* __restrict__ lg, const float* __restrict__ bias,
                        float* __restrict__ out, int M)
{
    int i = blockIdx.x * blockDim.x + threadIdx.x;
    if (i >= M) return;
    float o0 = lg[2 * (size_t)i + 0] + bias[0];
    float o1 = lg[2 * (size_t)i + 1] + bias[1];
    float m = fmaxf(o0, o1);
    float lse = m + logf(expf(o0 - m) + expf(o1 - m));
    out[2 * (size_t)i + 0] = o0 - lse;
    out[2 * (size_t)i + 1] = o1 - lse;
}

extern "C" void kernel_launch(void* const* d_in, const int* in_sizes, int n_in,
                              void* d_out, int out_size, void* d_ws, size_t ws_size,
                              hipStream_t stream) {
    const float* x   = (const float*)d_in[0];
    const int*   ei  = (const int*)d_in[1];
    const int*   src = ei;
    const int*   dst = ei + N_EDGES;
    const float* W1 = (const float*)d_in[2];  const float* b1 = (const float*)d_in[3];
    const float* W2 = (const float*)d_in[4];  const float* b2 = (const float*)d_in[5];
    const float* W3 = (const float*)d_in[6];  const float* b3 = (const float*)d_in[7];
    const float* W4 = (const float*)d_in[8];  const float* b4 = (const float*)d_in[9];
    const float* W5 = (const float*)d_in[10]; const float* b5 = (const float*)d_in[11];
    float* out = (float*)d_out;

    // ---- workspace (total ~210.8 MB) ----
    // [0,3M): dinv@0, cnt@256K, rowptr@512K, cursor@768K, csr@1M
    // [3M,6M): packed transposed weights
    // [6M,...): R0 [50000*512 words], R1 [50000*256], R2 [50000*256]
    char* ws = (char*)d_ws;
    float*    dinv   = (float*)(ws + 0);
    int*      cnt    = (int*)(ws + 256 * 1024);
    int*      rowptr = (int*)(ws + 512 * 1024);
    int*      cursor = (int*)(ws + 768 * 1024);
    int*      csr    = (int*)(ws + 1024 * 1024);
    unsigned* wt1 = (unsigned*)(ws + 3 * 1024 * 1024);
    unsigned* wt2 = wt1 + 128 * 256;
    unsigned* wt3 = wt2 + 256 * 512;
    unsigned* wt4 = wt3 + 512 * 256;

    char* D = ws + 6 * 1024 * 1024;
    float*    xs   = (float*)D;                                    // [50000][128] f32
    unsigned* aggx = (unsigned*)(D + (size_t)N_NODES * 128 * 4);   // [50000][128] packed
    unsigned* h1s  = (unsigned*)(D + (size_t)N_NODES * 512 * 4);   // R1: [50000][256]
    unsigned* a2   = (unsigned*)(D + (size_t)N_NODES * 768 * 4);   // R2: [50000][256]
    unsigned* h2   = (unsigned*)D;                                 // R0: [50000][512]
    unsigned* g3s  = h1s;                                          // R1 reuse
    unsigned* h3   = a2;                                           // R2 reuse
    unsigned* g4s  = (unsigned*)D;                                 // [50000][64]
    float*    h4   = (float*)(D + (size_t)N_NODES * 64 * 4);       // [50000][64] f32
    float*    g5s  = (float*)(D + (size_t)N_NODES * 128 * 4);      // [50000][2]
    float*    lgt  = (float*)(D + (size_t)N_NODES * 132 * 4);      // [50000][2]

    const int T = 256;
    const int nodeB = (N_NODES + T - 1) / T;
    const int edgeB = (N_EDGES + T - 1) / T;
    const int aggB  = (N_NODES + 3) / 4;
    const int gx    = (N_NODES + 127) / 128;

    // ---- CSR + dinv + weight prep ----
    k_zero_i<<<nodeB, T, 0, stream>>>(cnt, N_NODES);
    k_count<<<edgeB, T, 0, stream>>>(dst, cnt);
    k_scan<<<1, 1024, 0, stream>>>(cnt, rowptr, dinv, N_NODES);
    k_copy_i<<<nodeB, T, 0, stream>>>(rowptr, cursor, N_NODES);
    k_fill<<<edgeB, T, 0, stream>>>(src, dst, cursor, csr);
    k_wprep<<<(128 * 256 + T - 1) / T, T, 0, stream>>>(W1, wt1, 128, 256);
    k_wprep<<<(256 * 512 + T - 1) / T, T, 0, stream>>>(W2, wt2, 256, 512);
    k_wprep<<<(512 * 256 + T - 1) / T, T, 0, stream>>>(W3, wt3, 512, 256);
    k_wprep<<<(256 * 64 + T - 1) / T, T, 0, stream>>>(W4, wt4, 256, 64);

    // ---- L1: agg(128) -> GEMM 128->256, h1s = dinv*relu(+b1) ----
    k_rowscale<<<(N_NODES * 32 + T - 1) / T, T, 0, stream>>>(x, dinv, xs);
    k_agg<2, 0, 0, 1><<<aggB, T, 0, stream>>>(xs, rowptr, csr, dinv, nullptr, aggx);
    k_gemm_mfma<<<dim3(gx, 4), T, 0, stream>>>(aggx, wt1, dinv, b1, h1s, N_NODES, 128, 256, 2);

    // ---- L2: agg(256) -> GEMM 256->512, h2 = relu(+b2) ----
    k_agg<4, 0, 1, 1><<<aggB, T, 0, stream>>>(h1s, rowptr, csr, dinv, nullptr, a2);
    k_gemm_mfma<<<dim3(gx, 8), T, 0, stream>>>(a2, wt2, dinv, b2, h2, N_NODES, 256, 512, 1);

    // ---- L3: GEMM 512->256 (g3s = dinv*acc) -> agg w/ relu+b3 ----
    k_gemm_mfma<<<dim3(gx, 4), T, 0, stream>>>(h2, wt3, dinv, nullptr, g3s, N_NODES, 512, 256, 0);
    k_agg<4, 1, 1, 1><<<aggB, T, 0, stream>>>(g3s, rowptr, csr, dinv, b3, h3);

    // ---- L4: GEMM 256->64 -> agg w/ relu+b4 (f32 out) ----
    k_gemm_mfma<<<dim3(gx, 1), T, 0, stream>>>(h3, wt4, dinv, nullptr, g4s, N_NODES, 256, 64, 0);
    k_agg<1, 1, 1, 0><<<aggB, T, 0, stream>>>(g4s, rowptr, csr, dinv, b4, h4);

    // ---- L5: GEMM 64->2, agg, log_softmax ----
    k_gemm2<<<nodeB, T, 0, stream>>>(h4, W5, dinv, g5s, N_NODES, 64);
    k_agg2<<<nodeB, T, 0, stream>>>(g5s, rowptr, csr, dinv, lgt);
    k_final<<<nodeB, T, 0, stream>>>(lgt, b5, out, N_NODES);
}